// Round 4
// baseline (304.474 us; speedup 1.0000x reference)
//
#include <hip/hip_runtime.h>
#include <hip/hip_cooperative_groups.h>
#include <stdint.h>

// ---------------------------------------------------------------------------
// DualGatedRecurrence on MI355X.
// fwht() in the reference is the identity for D=1024 (butterfly S: S^2=2I;
// 10 steps = 32*I, cancelled by d^-0.5) => hproj(x,s) = x * prod_i(s_i).
// Pipeline (3 dispatches):
//   k_scan_fused (cooperative, 512 blocks): per-chunk local scans -> P,H;
//     weight prep + rowsum zero (fills grid-sync slack); grid.sync();
//     carry prefix from P/H (L2-hot) + rescan (x LLC-warm) -> xb, hcat.
//   GEMM1: 16x16x32 bf16 MFMA, BK=64, XOR-swizzled LDS (conflict-free),
//     XCD-aware remap; epilogue sigmoid*hcat + fused rowsum atomics.
//   GEMM2: same structure, rsqrt row-scale epilogue.
// GEMM = R0 proven version (48 us each); 8-phase variants killed (R1-R3:
// 3 structural variants all 23-24% MfmaUtil vs R0's 29% — documented dead).
// ---------------------------------------------------------------------------

namespace cg = cooperative_groups;

typedef __attribute__((ext_vector_type(8))) short short8;     // 8 bf16
typedef __attribute__((ext_vector_type(4))) float f32x4;
typedef __attribute__((ext_vector_type(2))) float f32x2;
typedef __attribute__((ext_vector_type(4))) unsigned short ushort4v;
typedef __attribute__((ext_vector_type(2))) unsigned short ushort2v;

typedef const __attribute__((address_space(1))) unsigned int* as1_u32p;
typedef __attribute__((address_space(3))) unsigned int* as3_u32p;

__device__ __forceinline__ void cp16(const void* g, void* l) {
  __builtin_amdgcn_global_load_lds((as1_u32p)(uintptr_t)g,
                                   (as3_u32p)(unsigned int)(uintptr_t)l,
                                   16, 0, 0);
}

__device__ __forceinline__ float b2f(unsigned short h) {
  union { unsigned int u; float f; } v; v.u = ((unsigned int)h) << 16; return v.f;
}
__device__ __forceinline__ unsigned short f2b(float f) {
  union { float f; unsigned int u; } v; v.f = f;
  unsigned int r = v.u + 0x7fffu + ((v.u >> 16) & 1u);   // round-nearest-even
  return (unsigned short)(r >> 16);
}
// fast sigmoid: hw exp + hw rcp (saves the ~9-op precise-div sequence)
__device__ __forceinline__ float sigmoidf_(float z) {
  return __builtin_amdgcn_rcpf(1.0f + __expf(-z));
}

// --------------- fused scan: local scan + prep | grid sync | rescan --------
// 512 blocks x 256 threads (2 blocks/CU, co-resident per cooperative launch).
// Thread (b, chunk, d-pair): chunk = 32 t-steps.  Registers (scale products,
// aggregates) persist across the grid sync — no reload in the rescan.
__global__ __launch_bounds__(256) void k_scan_fused(
    const float* __restrict__ x,
    const float* __restrict__ fgs, const float* __restrict__ fvs,
    const float* __restrict__ sgs, const float* __restrict__ svs,
    const float* __restrict__ fow, const float* __restrict__ sow,
    const float* __restrict__ mw,  const float* __restrict__ nw,
    float* __restrict__ PF, float* __restrict__ HF,
    float* __restrict__ PS, float* __restrict__ HS,
    unsigned short* __restrict__ wcat, unsigned short* __restrict__ w2,
    float* __restrict__ rowsum,
    unsigned short* __restrict__ xb, unsigned short* __restrict__ hcat) {
  const int g = blockIdx.x * 256 + threadIdx.x;   // 0..131071
  const int d0 = (g & 511) << 1;
  const int rest = g >> 9;
  const int chunk = rest & 63, b = rest >> 6;     // chunk,b block-uniform
  float fg0 = 1.f, fg1 = 1.f, fv0 = 1.f, fv1 = 1.f;
  float sg0 = 1.f, sg1 = 1.f, sv0 = 1.f, sv1 = 1.f;
#pragma unroll
  for (int i = 0; i < 5; ++i) {
    f32x2 a = *(const f32x2*)&fgs[i * 1024 + d0]; fg0 *= a.x; fg1 *= a.y;
    f32x2 bq = *(const f32x2*)&fvs[i * 1024 + d0]; fv0 *= bq.x; fv1 *= bq.y;
    f32x2 c = *(const f32x2*)&sgs[i * 1024 + d0]; sg0 *= c.x; sg1 *= c.y;
    f32x2 e = *(const f32x2*)&svs[i * 1024 + d0]; sv0 *= e.x; sv1 *= e.y;
  }
  const size_t base = ((size_t)(b * 2048 + chunk * 32)) * 1024 + d0;
  // ---- phase 1: local scan (store-free) ----
  {
    float pF0 = 1.f, hF0 = 0.f, pS0 = 1.f, hS0 = 0.f;
    float pF1 = 1.f, hF1 = 0.f, pS1 = 1.f, hS1 = 0.f;
#pragma unroll 8
    for (int t = 0; t < 32; ++t) {
      f32x2 xv = *(const f32x2*)&x[base + (size_t)t * 1024];
      float fF0 = sigmoidf_(xv.x * fg0 + 0.5f);
      hF0 = fF0 * hF0 + (1.f - fF0) * (xv.x * fv0); pF0 *= fF0;
      float fS0 = 0.85f + 0.15f * sigmoidf_(xv.x * sg0 + 0.5f);
      hS0 = fS0 * hS0 + (1.f - fS0) * (xv.x * sv0); pS0 *= fS0;
      float fF1 = sigmoidf_(xv.y * fg1 + 0.5f);
      hF1 = fF1 * hF1 + (1.f - fF1) * (xv.y * fv1); pF1 *= fF1;
      float fS1 = 0.85f + 0.15f * sigmoidf_(xv.y * sg1 + 0.5f);
      hS1 = fS1 * hS1 + (1.f - fS1) * (xv.y * sv1); pS1 *= fS1;
    }
    const int idx = (b * 64 + chunk) * 1024 + d0;
    *(f32x2*)&PF[idx] = f32x2{pF0, pF1};
    *(f32x2*)&HF[idx] = f32x2{hF0, hF1};
    *(f32x2*)&PS[idx] = f32x2{pS0, pS1};
    *(f32x2*)&HS[idx] = f32x2{hS0, hS1};
  }
  // ---- phase 2: weight prep (independent; fills grid-sync slack) ----
  // k=0,1 -> fow->wcat; k=2,3 -> sow->wcat; k=4..7 -> mw*nw->w2 (all static).
#pragma unroll
  for (int k = 0; k < 2; ++k) {
    const int i = (k * 131072 + g) * 4;
    f32x4 v = *(const f32x4*)&fow[i];
    ushort4v o = { f2b(v.x), f2b(v.y), f2b(v.z), f2b(v.w) };
    *(ushort4v*)&wcat[i] = o;
  }
#pragma unroll
  for (int k = 2; k < 4; ++k) {
    const int i = (k * 131072 + g) * 4;
    f32x4 v = *(const f32x4*)&sow[i - 1048576];
    ushort4v o = { f2b(v.x), f2b(v.y), f2b(v.z), f2b(v.w) };
    *(ushort4v*)&wcat[i] = o;
  }
#pragma unroll
  for (int k = 4; k < 8; ++k) {
    const int i = ((k - 4) * 131072 + g) * 4;
    const int m = i & 2047;
    f32x4 v = *(const f32x4*)&mw[i];
    f32x4 s = *(const f32x4*)&nw[m];
    ushort4v o = { f2b(v.x * s.x), f2b(v.y * s.y), f2b(v.z * s.z), f2b(v.w * s.w) };
    *(ushort4v*)&w2[i] = o;
  }
  if (g < 8192) rowsum[g] = 0.f;
  // ---- grid-wide barrier (device-scope fence included) ----
  cg::this_grid().sync();
  // ---- phase 3: carry-in from chunk aggregates 0..chunk-1 (L2-hot) ----
  float cF0 = 0.f, cF1 = 0.f, cS0 = 0.f, cS1 = 0.f;
  {
    const int base_i = b * 64 * 1024 + d0;
    int c = 0;
    for (; c + 4 <= chunk; c += 4) {
      f32x2 pf[4], hf[4], ps[4], hs[4];
#pragma unroll
      for (int j = 0; j < 4; ++j) {
        int i = base_i + (c + j) * 1024;
        pf[j] = *(const f32x2*)&PF[i]; hf[j] = *(const f32x2*)&HF[i];
        ps[j] = *(const f32x2*)&PS[i]; hs[j] = *(const f32x2*)&HS[i];
      }
#pragma unroll
      for (int j = 0; j < 4; ++j) {
        cF0 = hf[j].x + pf[j].x * cF0; cF1 = hf[j].y + pf[j].y * cF1;
        cS0 = hs[j].x + ps[j].x * cS0; cS1 = hs[j].y + ps[j].y * cS1;
      }
    }
    for (; c < chunk; ++c) {
      int i = base_i + c * 1024;
      f32x2 pf = *(const f32x2*)&PF[i], hf = *(const f32x2*)&HF[i];
      f32x2 ps = *(const f32x2*)&PS[i], hs = *(const f32x2*)&HS[i];
      cF0 = hf.x + pf.x * cF0; cF1 = hf.y + pf.y * cF1;
      cS0 = hs.x + ps.x * cS0; cS1 = hs.y + ps.y * cS1;
    }
  }
  // ---- phase 4: rescan (x LLC-warm) -> xb bf16, hcat bf16 ----
  float pF0 = 1.f, hF0 = 0.f, pS0 = 1.f, hS0 = 0.f;
  float pF1 = 1.f, hF1 = 0.f, pS1 = 1.f, hS1 = 0.f;
#pragma unroll 4
  for (int t = 0; t < 32; ++t) {
    f32x2 xv = *(const f32x2*)&x[base + (size_t)t * 1024];
    *(ushort2v*)&xb[base + (size_t)t * 1024] = ushort2v{f2b(xv.x), f2b(xv.y)};
    float fF0 = sigmoidf_(xv.x * fg0 + 0.5f);
    hF0 = fF0 * hF0 + (1.f - fF0) * (xv.x * fv0); pF0 *= fF0;
    float fS0 = 0.85f + 0.15f * sigmoidf_(xv.x * sg0 + 0.5f);
    hS0 = fS0 * hS0 + (1.f - fS0) * (xv.x * sv0); pS0 *= fS0;
    float fF1 = sigmoidf_(xv.y * fg1 + 0.5f);
    hF1 = fF1 * hF1 + (1.f - fF1) * (xv.y * fv1); pF1 *= fF1;
    float fS1 = 0.85f + 0.15f * sigmoidf_(xv.y * sg1 + 0.5f);
    hS1 = fS1 * hS1 + (1.f - fS1) * (xv.y * sv1); pS1 *= fS1;
    size_t bt = (size_t)(b * 2048 + chunk * 32 + t);
    *(ushort2v*)&hcat[bt * 2048 + d0] =
        ushort2v{f2b(hF0 + pF0 * cF0), f2b(hF1 + pF1 * cF1)};
    *(ushort2v*)&hcat[bt * 2048 + 1024 + d0] =
        ushort2v{f2b(hS0 + pS0 * cS0), f2b(hS1 + pS1 * cS1)};
  }
}

// ------------------------- bf16 MFMA GEMM, 16x16x32, BK=64, swizzled -------
// C[m,n] = sum_k A[m,k]*B[n,k].  Block tile (2*WM)x(2*WN), 4 waves 2x2, each
// wave WMxWN of 16x16 MFMA tiles, BK=64 (2 sub-steps per barrier pair).
// LDS row stride 64 elts; 16B-chunk slot = chunk ^ (row&7): conflict-free.
// Grid 1D, XCD remap: col=(n>>3)&(2^CB-1); band=(n&7)|((n>>(3+CB))<<3).
// MODE 1: merged = bf16(sigmoid(C)*hcat); rowsum[m] += sum_n v^2 (atomic)
// MODE 2: out = rsqrt(rowsum[m]/2048 + 1e-6) * C
template <int WM, int WN, int MODE, int CB>
__global__ __launch_bounds__(256, 4) void k_gemm(
    const unsigned short* __restrict__ A, const unsigned short* __restrict__ B,
    const int K,
    const unsigned short* __restrict__ hcat, unsigned short* __restrict__ merged,
    float* __restrict__ rowsum, float* __restrict__ out) {
  constexpr int BM = 2 * WM, BN = 2 * WN;
  constexpr int RA = BM / 32, RB = BN / 32;   // cp16 rounds (8 rows each)
  constexpr int AM = WM / 16, BT = WN / 16;
  __shared__ __align__(16) unsigned short sA[BM * 64];
  __shared__ __align__(16) unsigned short sB[BN * 64];
  const int tid = threadIdx.x, wv = tid >> 6, ln = tid & 63;
  const int n_ = blockIdx.x;
  const int col = (n_ >> 3) & ((1 << CB) - 1);
  const int band = (n_ & 7) | ((n_ >> (3 + CB)) << 3);
  const int bm = band * BM, bn = col * BN;

  const int srow = ln >> 3;                       // 0..7 within round
  const int clog = (ln & 7) ^ srow;               // swizzled logical chunk
  const unsigned short* gA[RA]; unsigned short* lA[RA];
  const unsigned short* gB[RB]; unsigned short* lB[RB];
#pragma unroll
  for (int j = 0; j < RA; ++j) {
    const int R0 = wv * (BM / 4) + j * 8;
    gA[j] = A + (size_t)(bm + R0 + srow) * K + clog * 8;
    lA[j] = &sA[R0 * 64 + ln * 8];
  }
#pragma unroll
  for (int j = 0; j < RB; ++j) {
    const int R0 = wv * (BN / 4) + j * 8;
    gB[j] = B + (size_t)(bn + R0 + srow) * K + clog * 8;
    lB[j] = &sB[R0 * 64 + ln * 8];
  }

  const int fr = ln & 15, fq = ln >> 4;           // frag row, chunk base 0..3
  const int wm = (wv >> 1) * WM, wn = (wv & 1) * WN;

  f32x4 acc[AM][BT];
  const f32x4 z4 = {0.f, 0.f, 0.f, 0.f};
#pragma unroll
  for (int i = 0; i < AM; ++i)
#pragma unroll
    for (int j = 0; j < BT; ++j) acc[i][j] = z4;

  for (int k0 = 0; k0 < K; k0 += 64) {
#pragma unroll
    for (int j = 0; j < RA; ++j) cp16(gA[j] + k0, lA[j]);
#pragma unroll
    for (int j = 0; j < RB; ++j) cp16(gB[j] + k0, lB[j]);
    __syncthreads();
#pragma unroll
    for (int sub = 0; sub < 2; ++sub) {
      short8 af[AM], bf[BT];
#pragma unroll
      for (int mi = 0; mi < AM; ++mi) {
        const int row = wm + mi * 16 + fr;
        const int slot = (fq + sub * 4) ^ (row & 7);
        af[mi] = *(const short8*)&sA[row * 64 + slot * 8];
      }
#pragma unroll
      for (int ni = 0; ni < BT; ++ni) {
        const int row = wn + ni * 16 + fr;
        const int slot = (fq + sub * 4) ^ (row & 7);
        bf[ni] = *(const short8*)&sB[row * 64 + slot * 8];
      }
#pragma unroll
      for (int mi = 0; mi < AM; ++mi)
#pragma unroll
        for (int ni = 0; ni < BT; ++ni)
          acc[mi][ni] = __builtin_amdgcn_mfma_f32_16x16x32_bf16(
              af[mi], bf[ni], acc[mi][ni], 0, 0, 0);
    }
    __syncthreads();
  }

  // C/D layout: col = lane&15, row = (lane>>4)*4 + reg   [verified m89/m91]
  const int er0 = fq * 4;
  if (MODE == 1) {
#pragma unroll
    for (int mi = 0; mi < AM; ++mi) {
#pragma unroll
      for (int r = 0; r < 4; ++r) {
        const int m = bm + wm + mi * 16 + er0 + r;
        float s = 0.f;
#pragma unroll
        for (int ni = 0; ni < BT; ++ni) {
          const int n = bn + wn + ni * 16 + fr;
          const size_t idx = (size_t)m * 2048 + n;
          float v = sigmoidf_(acc[mi][ni][r]) * b2f(hcat[idx]);
          merged[idx] = f2b(v);
          s += v * v;
        }
        s += __shfl_xor(s, 1); s += __shfl_xor(s, 2);
        s += __shfl_xor(s, 4); s += __shfl_xor(s, 8);
        if (fr == 0) atomicAdd(&rowsum[m], s);
      }
    }
  } else {
#pragma unroll
    for (int mi = 0; mi < AM; ++mi) {
#pragma unroll
      for (int r = 0; r < 4; ++r) {
        const int m = bm + wm + mi * 16 + er0 + r;
        const float rf = rsqrtf(rowsum[m] * (1.0f / 2048.0f) + 1e-6f);
#pragma unroll
        for (int ni = 0; ni < BT; ++ni) {
          const int n = bn + wn + ni * 16 + fr;
          out[(size_t)m * 1024 + n] = rf * acc[mi][ni][r];
        }
      }
    }
  }
}

// ---------------------------------------------------------------------------
extern "C" void kernel_launch(void* const* d_in, const int* in_sizes, int n_in,
                              void* d_out, int out_size, void* d_ws, size_t ws_size,
                              hipStream_t stream) {
  const float* x   = (const float*)d_in[0];
  const float* fgs = (const float*)d_in[1];
  const float* fvs = (const float*)d_in[2];
  const float* fow = (const float*)d_in[3];
  const float* sgs = (const float*)d_in[4];
  const float* svs = (const float*)d_in[5];
  const float* sow = (const float*)d_in[6];
  const float* mw  = (const float*)d_in[7];
  const float* nw  = (const float*)d_in[8];
  float* out = (float*)d_out;

  char* ws = (char*)d_ws;
  float* rowsum = (float*)(ws + 0);                         // 32 KB
  unsigned short* xb   = (unsigned short*)(ws + 32768);     // 16 MB
  unsigned short* wcat = (unsigned short*)(ws + 16809984);  // 4 MB
  unsigned short* w2   = (unsigned short*)(ws + 21004288);  // 4 MB
  unsigned short* hcat = (unsigned short*)(ws + 25198592);  // 32 MB
  unsigned short* mg   = (unsigned short*)(ws + 58753024);  // 32 MB (end ~92MB)
  // P/H (1 MB each) alias the mg region: P/H are dead before GEMM1 writes mg.
  float* PF = (float*)(ws + 58753024);
  float* HF = (float*)(ws + 58753024 + 1 * 1048576);
  float* PS = (float*)(ws + 58753024 + 2 * 1048576);
  float* HS = (float*)(ws + 58753024 + 3 * 1048576);

  // fused scan (cooperative: 512 blocks co-resident at 2 blocks/CU)
  void* kargs[] = {
    (void*)&x, (void*)&fgs, (void*)&fvs, (void*)&sgs, (void*)&svs,
    (void*)&fow, (void*)&sow, (void*)&mw, (void*)&nw,
    (void*)&PF, (void*)&HF, (void*)&PS, (void*)&HS,
    (void*)&wcat, (void*)&w2, (void*)&rowsum, (void*)&xb, (void*)&hcat };
  hipLaunchCooperativeKernel((const void*)k_scan_fused, dim3(512), dim3(256),
                             kargs, 0, stream);
  // GEMM1: M=8192, N=2048, K=1024; tile 128x128; 64 bands x 16 cols
  k_gemm<64, 64, 1, 4><<<1024, 256, 0, stream>>>(
      xb, wcat, 1024, hcat, mg, rowsum, nullptr);
  // GEMM2: M=8192, N=1024, K=2048; tile 64x128; 128 bands x 8 cols
  k_gemm<32, 64, 2, 3><<<1024, 256, 0, stream>>>(
      mg, w2, 2048, nullptr, nullptr, rowsum, out);
}

// Round 5
// 208.548 us; speedup vs baseline: 1.4600x; 1.4600x over previous
//
#include <hip/hip_runtime.h>
#include <stdint.h>

// ---------------------------------------------------------------------------
// DualGatedRecurrence on MI355X.
// fwht() in the reference is the identity for D=1024 (butterfly S: S^2=2I;
// 10 steps = 32*I, cancelled by d^-0.5) => hproj(x,s) = x * prod_i(s_i).
// Pipeline (3 dispatches; R4 post-mortem: ~80us of wall is launch/graph
// overhead, so fewer+denser dispatches; cooperative fusion killed in R4,
// 8-phase GEMM killed in R1-R3):
//   scanA+prep: per-chunk local scans -> P,H aggregates; xb = bf16(x);
//     weight prep to bf16; rowsum zero.
//   GEMM1: 16x16x32 bf16 MFMA, BK=64, XOR-swizzled LDS, XCD-aware remap.
//     TAIL rebuilds its own 128x128 h-tile in LDS (carry combine from P/H
//     aggregates + 64-step rescan of x) -- hcat is never materialized in
//     HBM (saves 32MB write + 32MB read + the whole scanC dispatch).
//     Epilogue: sigmoid(C)*h_tile -> mg, fused rowsum atomics.
//   GEMM2: same GEMM structure, rsqrt row-scale epilogue.
// ---------------------------------------------------------------------------

typedef __attribute__((ext_vector_type(8))) short short8;     // 8 bf16
typedef __attribute__((ext_vector_type(4))) float f32x4;
typedef __attribute__((ext_vector_type(2))) float f32x2;
typedef __attribute__((ext_vector_type(4))) unsigned short ushort4v;
typedef __attribute__((ext_vector_type(2))) unsigned short ushort2v;

typedef const __attribute__((address_space(1))) unsigned int* as1_u32p;
typedef __attribute__((address_space(3))) unsigned int* as3_u32p;

__device__ __forceinline__ void cp16(const void* g, void* l) {
  __builtin_amdgcn_global_load_lds((as1_u32p)(uintptr_t)g,
                                   (as3_u32p)(unsigned int)(uintptr_t)l,
                                   16, 0, 0);
}

__device__ __forceinline__ float b2f(unsigned short h) {
  union { unsigned int u; float f; } v; v.u = ((unsigned int)h) << 16; return v.f;
}
__device__ __forceinline__ unsigned short f2b(float f) {
  union { float f; unsigned int u; } v; v.f = f;
  unsigned int r = v.u + 0x7fffu + ((v.u >> 16) & 1u);   // round-nearest-even
  return (unsigned short)(r >> 16);
}
// fast sigmoid: hw exp + hw rcp (saves the ~9-op precise-div sequence)
__device__ __forceinline__ float sigmoidf_(float z) {
  return __builtin_amdgcn_rcpf(1.0f + __expf(-z));
}

// ---------------- scanA (blocks 0..511) + prep (blocks 512..4639) ----------
// scan: (b, chunk, d-pair): 4 x 64 x 512 threads. chunk = 32 t-steps.
// Emits P (gate products), H (local end states), and xb = bf16(x).
__global__ __launch_bounds__(256) void k_scanA(
    const float* __restrict__ x,
    const float* __restrict__ fgs, const float* __restrict__ fvs,
    const float* __restrict__ sgs, const float* __restrict__ svs,
    const float* __restrict__ fow, const float* __restrict__ sow,
    const float* __restrict__ mw,  const float* __restrict__ nw,
    float* __restrict__ PF, float* __restrict__ HF,
    float* __restrict__ PS, float* __restrict__ HS,
    unsigned short* __restrict__ wcat, unsigned short* __restrict__ w2,
    float* __restrict__ rowsum, unsigned short* __restrict__ xb) {
  if (blockIdx.x >= 512) {                 // ---- prep part ----
    int g = (blockIdx.x - 512) * 256 + threadIdx.x;   // 0..1056767
    if (g < 524288) {
      int i = g * 4;
      const float* src = (i < 1048576) ? (fow + i) : (sow + (i - 1048576));
      f32x4 v = *(const f32x4*)src;
      ushort4v o = { f2b(v.x), f2b(v.y), f2b(v.z), f2b(v.w) };
      *(ushort4v*)&wcat[i] = o;
    } else if (g < 1048576) {
      int i = (g - 524288) * 4;
      int m = i & 2047;
      f32x4 v = *(const f32x4*)&mw[i];
      f32x4 s = *(const f32x4*)&nw[m];
      ushort4v o = { f2b(v.x * s.x), f2b(v.y * s.y), f2b(v.z * s.z), f2b(v.w * s.w) };
      *(ushort4v*)&w2[i] = o;
    } else if (g < 1056768) {
      rowsum[g - 1048576] = 0.f;
    }
    return;
  }
  // ---- scan part ----
  int g = blockIdx.x * 256 + threadIdx.x;   // 0..131071
  int d0 = (g & 511) << 1;
  int rest = g >> 9;
  int chunk = rest & 63, b = rest >> 6;
  float fg0 = 1.f, fg1 = 1.f, fv0 = 1.f, fv1 = 1.f;
  float sg0 = 1.f, sg1 = 1.f, sv0 = 1.f, sv1 = 1.f;
#pragma unroll
  for (int i = 0; i < 5; ++i) {
    f32x2 a = *(const f32x2*)&fgs[i * 1024 + d0]; fg0 *= a.x; fg1 *= a.y;
    f32x2 bq = *(const f32x2*)&fvs[i * 1024 + d0]; fv0 *= bq.x; fv1 *= bq.y;
    f32x2 c = *(const f32x2*)&sgs[i * 1024 + d0]; sg0 *= c.x; sg1 *= c.y;
    f32x2 e = *(const f32x2*)&svs[i * 1024 + d0]; sv0 *= e.x; sv1 *= e.y;
  }
  size_t base = ((size_t)(b * 2048 + chunk * 32)) * 1024 + d0;
  float pF0 = 1.f, hF0 = 0.f, pS0 = 1.f, hS0 = 0.f;
  float pF1 = 1.f, hF1 = 0.f, pS1 = 1.f, hS1 = 0.f;
#pragma unroll 8
  for (int t = 0; t < 32; ++t) {
    f32x2 xv = *(const f32x2*)&x[base + (size_t)t * 1024];
    *(ushort2v*)&xb[base + (size_t)t * 1024] = ushort2v{f2b(xv.x), f2b(xv.y)};
    float fF0 = sigmoidf_(xv.x * fg0 + 0.5f);
    hF0 = fF0 * hF0 + (1.f - fF0) * (xv.x * fv0); pF0 *= fF0;
    float fS0 = 0.85f + 0.15f * sigmoidf_(xv.x * sg0 + 0.5f);
    hS0 = fS0 * hS0 + (1.f - fS0) * (xv.x * sv0); pS0 *= fS0;
    float fF1 = sigmoidf_(xv.y * fg1 + 0.5f);
    hF1 = fF1 * hF1 + (1.f - fF1) * (xv.y * fv1); pF1 *= fF1;
    float fS1 = 0.85f + 0.15f * sigmoidf_(xv.y * sg1 + 0.5f);
    hS1 = fS1 * hS1 + (1.f - fS1) * (xv.y * sv1); pS1 *= fS1;
  }
  int idx = (b * 64 + chunk) * 1024 + d0;
  *(f32x2*)&PF[idx] = f32x2{pF0, pF1};
  *(f32x2*)&HF[idx] = f32x2{hF0, hF1};
  *(f32x2*)&PS[idx] = f32x2{pS0, pS1};
  *(f32x2*)&HS[idx] = f32x2{hS0, hS1};
}

// ------------------------- bf16 MFMA GEMM, 16x16x32, BK=64, swizzled -------
// C[m,n] = sum_k A[m,k]*B[n,k].  Block tile (2*WM)x(2*WN), 4 waves 2x2, each
// wave WMxWN of 16x16 MFMA tiles, BK=64 (2 sub-steps per barrier pair).
// LDS row stride 64 elts; 16B-chunk slot = chunk ^ (row&7): conflict-free.
// Grid 1D, XCD remap: col=(n>>3)&(2^CB-1); band=(n&7)|((n>>(3+CB))<<3).
// MODE 1 tail: rebuild h-tile [128 t][128 d] into LDS (reusing sA/sB, exactly
//   32KB): carry = sequential combine of P/H chunk aggregates for this
//   block's (b, d-cols) up to its t-band (L2-hot, coalesced), then 64-step
//   rescan of x (f32, L3-warm). Thread map: tid&127 = d-col, tid>>7 = t-half.
//   Epilogue: merged = bf16(sigmoid(C)*h); rowsum[m] += sum_n v^2 (atomic).
// MODE 2: out = rsqrt(rowsum[m]/2048 + 1e-6) * C
template <int WM, int WN, int MODE, int CB>
__global__ __launch_bounds__(256, 4) void k_gemm(
    const unsigned short* __restrict__ A, const unsigned short* __restrict__ B,
    const int K,
    unsigned short* __restrict__ merged,
    float* __restrict__ rowsum, float* __restrict__ out,
    const float* __restrict__ xf,
    const float* __restrict__ fgs, const float* __restrict__ fvs,
    const float* __restrict__ sgs, const float* __restrict__ svs,
    const float* __restrict__ PF, const float* __restrict__ HF,
    const float* __restrict__ PS, const float* __restrict__ HS) {
  constexpr int BM = 2 * WM, BN = 2 * WN;
  constexpr int RA = BM / 32, RB = BN / 32;   // cp16 rounds (8 rows each)
  constexpr int AM = WM / 16, BT = WN / 16;
  __shared__ __align__(16) unsigned short sAB[(BM + BN) * 64];
  unsigned short* sA = sAB;
  unsigned short* sB = sAB + BM * 64;
  const int tid = threadIdx.x, wv = tid >> 6, ln = tid & 63;
  const int n_ = blockIdx.x;
  const int col = (n_ >> 3) & ((1 << CB) - 1);
  const int band = (n_ & 7) | ((n_ >> (3 + CB)) << 3);
  const int bm = band * BM, bn = col * BN;

  const int srow = ln >> 3;                       // 0..7 within round
  const int clog = (ln & 7) ^ srow;               // swizzled logical chunk
  const unsigned short* gA[RA]; unsigned short* lA[RA];
  const unsigned short* gB[RB]; unsigned short* lB[RB];
#pragma unroll
  for (int j = 0; j < RA; ++j) {
    const int R0 = wv * (BM / 4) + j * 8;
    gA[j] = A + (size_t)(bm + R0 + srow) * K + clog * 8;
    lA[j] = &sA[R0 * 64 + ln * 8];
  }
#pragma unroll
  for (int j = 0; j < RB; ++j) {
    const int R0 = wv * (BN / 4) + j * 8;
    gB[j] = B + (size_t)(bn + R0 + srow) * K + clog * 8;
    lB[j] = &sB[R0 * 64 + ln * 8];
  }

  const int fr = ln & 15, fq = ln >> 4;           // frag row, chunk base 0..3
  const int wm = (wv >> 1) * WM, wn = (wv & 1) * WN;

  f32x4 acc[AM][BT];
  const f32x4 z4 = {0.f, 0.f, 0.f, 0.f};
#pragma unroll
  for (int i = 0; i < AM; ++i)
#pragma unroll
    for (int j = 0; j < BT; ++j) acc[i][j] = z4;

  for (int k0 = 0; k0 < K; k0 += 64) {
#pragma unroll
    for (int j = 0; j < RA; ++j) cp16(gA[j] + k0, lA[j]);
#pragma unroll
    for (int j = 0; j < RB; ++j) cp16(gB[j] + k0, lB[j]);
    __syncthreads();
#pragma unroll
    for (int sub = 0; sub < 2; ++sub) {
      short8 af[AM], bf[BT];
#pragma unroll
      for (int mi = 0; mi < AM; ++mi) {
        const int row = wm + mi * 16 + fr;
        const int slot = (fq + sub * 4) ^ (row & 7);
        af[mi] = *(const short8*)&sA[row * 64 + slot * 8];
      }
#pragma unroll
      for (int ni = 0; ni < BT; ++ni) {
        const int row = wn + ni * 16 + fr;
        const int slot = (fq + sub * 4) ^ (row & 7);
        bf[ni] = *(const short8*)&sB[row * 64 + slot * 8];
      }
#pragma unroll
      for (int mi = 0; mi < AM; ++mi)
#pragma unroll
        for (int ni = 0; ni < BT; ++ni)
          acc[mi][ni] = __builtin_amdgcn_mfma_f32_16x16x32_bf16(
              af[mi], bf[ni], acc[mi][ni], 0, 0, 0);
    }
    __syncthreads();
  }

  // C/D layout: col = lane&15, row = (lane>>4)*4 + reg   [verified m89/m91]
  const int er0 = fq * 4;
  if constexpr (MODE == 1) {
    static_assert((BM + BN) * 64 >= 128 * 128, "sH needs 32KB");
    // ---- tail: rebuild h-tile [128 t][128 d] into LDS (replaces hcat) ----
    // (safe to overwrite sAB: all waves passed the loop's final barrier)
    const bool isSlow = (bn >= 1024);
    const int dbase = isSlow ? (bn - 1024) : bn;
    const int bb = bm >> 11, t0 = bm & 2047, c0 = t0 >> 5;
    const int dcol = tid & 127, th = tid >> 7;     // th: t-half (0..63/64..127)
    const int d = dbase + dcol;
    const float* gsp = isSlow ? sgs : fgs;
    const float* vsp = isSlow ? svs : fvs;
    float gp = 1.f, vp = 1.f;
#pragma unroll
    for (int i = 0; i < 5; ++i) { gp *= gsp[i * 1024 + d]; vp *= vsp[i * 1024 + d]; }
    const float* Pp = isSlow ? PS : PF;
    const float* Hp = isSlow ? HS : HF;
    const int cend = c0 + th * 2;                  // carry-in chunk index
    const int pbase = bb * 65536 + d;              // b*64*1024 + d
    float h = 0.f;
    {
      int c = 0;
      for (; c + 4 <= cend; c += 4) {              // 4-batched for load pipelining
        float pv[4], hv[4];
#pragma unroll
        for (int j = 0; j < 4; ++j) {
          int i = pbase + (c + j) * 1024;
          pv[j] = Pp[i]; hv[j] = Hp[i];
        }
#pragma unroll
        for (int j = 0; j < 4; ++j) h = hv[j] + pv[j] * h;
      }
      for (; c < cend; ++c) {
        int i = pbase + c * 1024;
        h = Hp[i] + Pp[i] * h;
      }
    }
    unsigned short* sH = sAB;                      // [128 t][128 d] bf16
    size_t xbase = ((size_t)(bb * 2048 + t0 + th * 64)) * 1024 + d;
#pragma unroll 4
    for (int tt = 0; tt < 64; ++tt) {
      float xv = xf[xbase + (size_t)tt * 1024];
      float f = sigmoidf_(xv * gp + 0.5f);
      if (isSlow) f = 0.85f + 0.15f * f;
      h = f * h + (1.f - f) * (xv * vp);
      sH[(th * 64 + tt) * 128 + dcol] = f2b(h);
    }
    __syncthreads();
    // ---- epilogue: sigmoid(C) * h, rowsum atomics ----
#pragma unroll
    for (int mi = 0; mi < AM; ++mi) {
#pragma unroll
      for (int r = 0; r < 4; ++r) {
        const int mo = wm + mi * 16 + er0 + r;     // row within band
        const int m = bm + mo;
        float s = 0.f;
#pragma unroll
        for (int ni = 0; ni < BT; ++ni) {
          const int no = wn + ni * 16 + fr;        // col within tile
          float v = sigmoidf_(acc[mi][ni][r]) * b2f(sH[mo * 128 + no]);
          merged[(size_t)m * 2048 + bn + no] = f2b(v);
          s += v * v;
        }
        s += __shfl_xor(s, 1); s += __shfl_xor(s, 2);
        s += __shfl_xor(s, 4); s += __shfl_xor(s, 8);
        if (fr == 0) atomicAdd(&rowsum[m], s);
      }
    }
  } else {
#pragma unroll
    for (int mi = 0; mi < AM; ++mi) {
#pragma unroll
      for (int r = 0; r < 4; ++r) {
        const int m = bm + wm + mi * 16 + er0 + r;
        const float rf = rsqrtf(rowsum[m] * (1.0f / 2048.0f) + 1e-6f);
#pragma unroll
        for (int ni = 0; ni < BT; ++ni) {
          const int n = bn + wn + ni * 16 + fr;
          out[(size_t)m * 1024 + n] = rf * acc[mi][ni][r];
        }
      }
    }
  }
}

// ---------------------------------------------------------------------------
extern "C" void kernel_launch(void* const* d_in, const int* in_sizes, int n_in,
                              void* d_out, int out_size, void* d_ws, size_t ws_size,
                              hipStream_t stream) {
  const float* x   = (const float*)d_in[0];
  const float* fgs = (const float*)d_in[1];
  const float* fvs = (const float*)d_in[2];
  const float* fow = (const float*)d_in[3];
  const float* sgs = (const float*)d_in[4];
  const float* svs = (const float*)d_in[5];
  const float* sow = (const float*)d_in[6];
  const float* mw  = (const float*)d_in[7];
  const float* nw  = (const float*)d_in[8];
  float* out = (float*)d_out;

  char* ws = (char*)d_ws;
  float* rowsum = (float*)(ws + 0);                         // 32 KB
  unsigned short* xb   = (unsigned short*)(ws + 32768);     // 16 MB
  unsigned short* wcat = (unsigned short*)(ws + 16809984);  // 4 MB
  unsigned short* w2   = (unsigned short*)(ws + 21004288);  // 4 MB
  // P/H live through GEMM1 now (its tail reads them) -> they get their own
  // region (the freed hcat space), NOT the mg alias used in earlier rounds.
  float* PF = (float*)(ws + 25198592);                      // 1 MB each
  float* HF = (float*)(ws + 25198592 + 1 * 1048576);
  float* PS = (float*)(ws + 25198592 + 2 * 1048576);
  float* HS = (float*)(ws + 25198592 + 3 * 1048576);
  unsigned short* mg = (unsigned short*)(ws + 58753024);    // 32 MB (end ~92MB)

  // scan (blocks 0..511, emits P/H + xb) + weight prep (blocks 512..4639)
  k_scanA<<<4640, 256, 0, stream>>>(x, fgs, fvs, sgs, svs, fow, sow, mw, nw,
                                    PF, HF, PS, HS, wcat, w2, rowsum, xb);
  // GEMM1: M=8192, N=2048, K=1024; tile 128x128; 64 bands x 16 cols
  // tail rebuilds h in-block from P/H + x (no hcat in HBM)
  k_gemm<64, 64, 1, 4><<<1024, 256, 0, stream>>>(
      xb, wcat, 1024, mg, rowsum, nullptr,
      x, fgs, fvs, sgs, svs, PF, HF, PS, HS);
  // GEMM2: M=8192, N=1024, K=2048; tile 64x128; 128 bands x 8 cols
  k_gemm<32, 64, 2, 3><<<1024, 256, 0, stream>>>(
      mg, w2, 2048, nullptr, rowsum, out,
      nullptr, nullptr, nullptr, nullptr, nullptr,
      nullptr, nullptr, nullptr, nullptr);
}

// Round 6
// 201.987 us; speedup vs baseline: 1.5074x; 1.0325x over previous
//
#include <hip/hip_runtime.h>
#include <stdint.h>

// ---------------------------------------------------------------------------
// DualGatedRecurrence on MI355X.
// fwht() in the reference is the identity for D=1024 (butterfly S: S^2=2I;
// 10 steps = 32*I, cancelled by d^-0.5) => hproj(x,s) = x * prod_i(s_i).
// Pipeline (4 dispatches; marginal dispatch cost measured small in R0/R5):
//   scanA+prep: per-chunk local scans -> P,H aggregates; xb = bf16(x);
//     weight prep to bf16; rowsum zero.
//   k_prefix (tiny, 16 blocks): exclusive scan of chunk aggregates ->
//     C[b][chunk][d] carry-in table (replaces GEMM1's serial P/H chain).
//   GEMM1: 16x16x32 bf16 MFMA, BK=64, XOR-swizzled LDS, XCD-aware remap.
//     TAIL rebuilds its 128x128 h-tile in LDS: carry = ONE load from C
//     (hoisted above the K-loop with the scale products), then 64-step
//     rescan of x. sH XOR-swizzled (R5 had 8-way read conflict, 524K).
//     hcat never exists in HBM. Epilogue: sigmoid(C)*h -> mg + rowsum.
//   GEMM2: same GEMM structure, rsqrt row-scale epilogue.
// Killed branches: 8-phase GEMM (R1-R3, 23-24% MfmaUtil vs R0 29%),
// cooperative fusion (R4, 304 us).
// ---------------------------------------------------------------------------

typedef __attribute__((ext_vector_type(8))) short short8;     // 8 bf16
typedef __attribute__((ext_vector_type(4))) float f32x4;
typedef __attribute__((ext_vector_type(2))) float f32x2;
typedef __attribute__((ext_vector_type(4))) unsigned short ushort4v;
typedef __attribute__((ext_vector_type(2))) unsigned short ushort2v;

typedef const __attribute__((address_space(1))) unsigned int* as1_u32p;
typedef __attribute__((address_space(3))) unsigned int* as3_u32p;

__device__ __forceinline__ void cp16(const void* g, void* l) {
  __builtin_amdgcn_global_load_lds((as1_u32p)(uintptr_t)g,
                                   (as3_u32p)(unsigned int)(uintptr_t)l,
                                   16, 0, 0);
}

__device__ __forceinline__ float b2f(unsigned short h) {
  union { unsigned int u; float f; } v; v.u = ((unsigned int)h) << 16; return v.f;
}
__device__ __forceinline__ unsigned short f2b(float f) {
  union { float f; unsigned int u; } v; v.f = f;
  unsigned int r = v.u + 0x7fffu + ((v.u >> 16) & 1u);   // round-nearest-even
  return (unsigned short)(r >> 16);
}
// fast sigmoid: hw exp + hw rcp (saves the ~9-op precise-div sequence)
__device__ __forceinline__ float sigmoidf_(float z) {
  return __builtin_amdgcn_rcpf(1.0f + __expf(-z));
}

// ---------------- scanA (blocks 0..511) + prep (blocks 512..4639) ----------
// scan: (b, chunk, d-pair): 4 x 64 x 512 threads. chunk = 32 t-steps.
// Emits P (gate products), H (local end states), and xb = bf16(x).
__global__ __launch_bounds__(256) void k_scanA(
    const float* __restrict__ x,
    const float* __restrict__ fgs, const float* __restrict__ fvs,
    const float* __restrict__ sgs, const float* __restrict__ svs,
    const float* __restrict__ fow, const float* __restrict__ sow,
    const float* __restrict__ mw,  const float* __restrict__ nw,
    float* __restrict__ PF, float* __restrict__ HF,
    float* __restrict__ PS, float* __restrict__ HS,
    unsigned short* __restrict__ wcat, unsigned short* __restrict__ w2,
    float* __restrict__ rowsum, unsigned short* __restrict__ xb) {
  if (blockIdx.x >= 512) {                 // ---- prep part ----
    int g = (blockIdx.x - 512) * 256 + threadIdx.x;   // 0..1056767
    if (g < 524288) {
      int i = g * 4;
      const float* src = (i < 1048576) ? (fow + i) : (sow + (i - 1048576));
      f32x4 v = *(const f32x4*)src;
      ushort4v o = { f2b(v.x), f2b(v.y), f2b(v.z), f2b(v.w) };
      *(ushort4v*)&wcat[i] = o;
    } else if (g < 1048576) {
      int i = (g - 524288) * 4;
      int m = i & 2047;
      f32x4 v = *(const f32x4*)&mw[i];
      f32x4 s = *(const f32x4*)&nw[m];
      ushort4v o = { f2b(v.x * s.x), f2b(v.y * s.y), f2b(v.z * s.z), f2b(v.w * s.w) };
      *(ushort4v*)&w2[i] = o;
    } else if (g < 1056768) {
      rowsum[g - 1048576] = 0.f;
    }
    return;
  }
  // ---- scan part ----
  int g = blockIdx.x * 256 + threadIdx.x;   // 0..131071
  int d0 = (g & 511) << 1;
  int rest = g >> 9;
  int chunk = rest & 63, b = rest >> 6;
  float fg0 = 1.f, fg1 = 1.f, fv0 = 1.f, fv1 = 1.f;
  float sg0 = 1.f, sg1 = 1.f, sv0 = 1.f, sv1 = 1.f;
#pragma unroll
  for (int i = 0; i < 5; ++i) {
    f32x2 a = *(const f32x2*)&fgs[i * 1024 + d0]; fg0 *= a.x; fg1 *= a.y;
    f32x2 bq = *(const f32x2*)&fvs[i * 1024 + d0]; fv0 *= bq.x; fv1 *= bq.y;
    f32x2 c = *(const f32x2*)&sgs[i * 1024 + d0]; sg0 *= c.x; sg1 *= c.y;
    f32x2 e = *(const f32x2*)&svs[i * 1024 + d0]; sv0 *= e.x; sv1 *= e.y;
  }
  size_t base = ((size_t)(b * 2048 + chunk * 32)) * 1024 + d0;
  float pF0 = 1.f, hF0 = 0.f, pS0 = 1.f, hS0 = 0.f;
  float pF1 = 1.f, hF1 = 0.f, pS1 = 1.f, hS1 = 0.f;
#pragma unroll 8
  for (int t = 0; t < 32; ++t) {
    f32x2 xv = *(const f32x2*)&x[base + (size_t)t * 1024];
    *(ushort2v*)&xb[base + (size_t)t * 1024] = ushort2v{f2b(xv.x), f2b(xv.y)};
    float fF0 = sigmoidf_(xv.x * fg0 + 0.5f);
    hF0 = fF0 * hF0 + (1.f - fF0) * (xv.x * fv0); pF0 *= fF0;
    float fS0 = 0.85f + 0.15f * sigmoidf_(xv.x * sg0 + 0.5f);
    hS0 = fS0 * hS0 + (1.f - fS0) * (xv.x * sv0); pS0 *= fS0;
    float fF1 = sigmoidf_(xv.y * fg1 + 0.5f);
    hF1 = fF1 * hF1 + (1.f - fF1) * (xv.y * fv1); pF1 *= fF1;
    float fS1 = 0.85f + 0.15f * sigmoidf_(xv.y * sg1 + 0.5f);
    hS1 = fS1 * hS1 + (1.f - fS1) * (xv.y * sv1); pS1 *= fS1;
  }
  int idx = (b * 64 + chunk) * 1024 + d0;
  *(f32x2*)&PF[idx] = f32x2{pF0, pF1};
  *(f32x2*)&HF[idx] = f32x2{hF0, hF1};
  *(f32x2*)&PS[idx] = f32x2{pS0, pS1};
  *(f32x2*)&HS[idx] = f32x2{hS0, hS1};
}

// ---------------- k_prefix: chunk-level exclusive carry scan ---------------
// C[b][c][d] = carry INTO chunk c = fold_{j<c} (h_j + p_j * .): 16 blocks,
// thread = (fs, b, d-pair), serial over 64 chunks, loads batched by 4.
// Replaces GEMM1's per-block O(band) dependent-load chain with 1 load.
__global__ __launch_bounds__(256) void k_prefix(
    const float* __restrict__ PF, const float* __restrict__ HF,
    const float* __restrict__ PS, const float* __restrict__ HS,
    float* __restrict__ CF, float* __restrict__ CS) {
  const int g = blockIdx.x * 256 + threadIdx.x;   // 0..4095
  const int dp = g & 511;
  const int b  = (g >> 9) & 3;
  const int fs = g >> 11;                         // 0=fast 1=slow
  const float* P = fs ? PS : PF;
  const float* H = fs ? HS : HF;
  float*       C = fs ? CS : CF;
  const int base = b * 65536 + dp * 2;
  float c0 = 0.f, c1 = 0.f;
  *(f32x2*)&C[base] = f32x2{0.f, 0.f};
  for (int c = 0; c < 60; c += 4) {
    f32x2 p[4], h[4];
#pragma unroll
    for (int j = 0; j < 4; ++j) {
      p[j] = *(const f32x2*)&P[base + (c + j) * 1024];
      h[j] = *(const f32x2*)&H[base + (c + j) * 1024];
    }
#pragma unroll
    for (int j = 0; j < 4; ++j) {
      c0 = h[j].x + p[j].x * c0;
      c1 = h[j].y + p[j].y * c1;
      *(f32x2*)&C[base + (c + j + 1) * 1024] = f32x2{c0, c1};
    }
  }
#pragma unroll
  for (int c = 60; c < 63; ++c) {
    f32x2 p = *(const f32x2*)&P[base + c * 1024];
    f32x2 h = *(const f32x2*)&H[base + c * 1024];
    c0 = h.x + p.x * c0; c1 = h.y + p.y * c1;
    *(f32x2*)&C[base + (c + 1) * 1024] = f32x2{c0, c1};
  }
}

// ------------------------- bf16 MFMA GEMM, 16x16x32, BK=64, swizzled -------
// C[m,n] = sum_k A[m,k]*B[n,k].  Block tile (2*WM)x(2*WN), 4 waves 2x2, each
// wave WMxWN of 16x16 MFMA tiles, BK=64 (2 sub-steps per barrier pair).
// LDS row stride 64 elts; 16B-chunk slot = chunk ^ (row&7): conflict-free.
// Grid 1D, XCD remap: col=(n>>3)&(2^CB-1); band=(n&7)|((n>>(3+CB))<<3).
// MODE 1 tail: carry-in = 1 load from Cp (hoisted pre-K-loop with gp/vp),
//   then 64-step rescan of x -> sH [128 t][128 d] bf16 in LDS (reuses sAB,
//   exactly 32KB). sH XOR-swizzle col^(((row>>2)&3)<<4): epilogue mask is
//   exactly fq<<4 -> 4 fq-groups hit 4 disjoint 8-bank blocks (2 lanes/bank,
//   free per m136); write side is wave-uniform mask (still conflict-free).
//   Epilogue: merged = bf16(sigmoid(C)*h); rowsum[m] += sum_n v^2 (atomic).
// MODE 2: out = rsqrt(rowsum[m]/2048 + 1e-6) * C
template <int WM, int WN, int MODE, int CB>
__global__ __launch_bounds__(256, 4) void k_gemm(
    const unsigned short* __restrict__ A, const unsigned short* __restrict__ B,
    const int K,
    unsigned short* __restrict__ merged,
    float* __restrict__ rowsum, float* __restrict__ out,
    const float* __restrict__ xf,
    const float* __restrict__ fgs, const float* __restrict__ fvs,
    const float* __restrict__ sgs, const float* __restrict__ svs,
    const float* __restrict__ CF, const float* __restrict__ CS) {
  constexpr int BM = 2 * WM, BN = 2 * WN;
  constexpr int RA = BM / 32, RB = BN / 32;   // cp16 rounds (8 rows each)
  constexpr int AM = WM / 16, BT = WN / 16;
  __shared__ __align__(16) unsigned short sAB[(BM + BN) * 64];
  unsigned short* sA = sAB;
  unsigned short* sB = sAB + BM * 64;
  const int tid = threadIdx.x, wv = tid >> 6, ln = tid & 63;
  const int n_ = blockIdx.x;
  const int col = (n_ >> 3) & ((1 << CB) - 1);
  const int band = (n_ & 7) | ((n_ >> (3 + CB)) << 3);
  const int bm = band * BM, bn = col * BN;

  const int srow = ln >> 3;                       // 0..7 within round
  const int clog = (ln & 7) ^ srow;               // swizzled logical chunk
  const unsigned short* gA[RA]; unsigned short* lA[RA];
  const unsigned short* gB[RB]; unsigned short* lB[RB];
#pragma unroll
  for (int j = 0; j < RA; ++j) {
    const int R0 = wv * (BM / 4) + j * 8;
    gA[j] = A + (size_t)(bm + R0 + srow) * K + clog * 8;
    lA[j] = &sA[R0 * 64 + ln * 8];
  }
#pragma unroll
  for (int j = 0; j < RB; ++j) {
    const int R0 = wv * (BN / 4) + j * 8;
    gB[j] = B + (size_t)(bn + R0 + srow) * K + clog * 8;
    lB[j] = &sB[R0 * 64 + ln * 8];
  }

  const int fr = ln & 15, fq = ln >> 4;           // frag row, chunk base 0..3
  const int wm = (wv >> 1) * WM, wn = (wv & 1) * WN;

  // ---- MODE1 tail-prep, hoisted: completes under the K-loop (~8 VGPR) ----
  float gp = 1.f, vp = 1.f, hcar = 0.f;
  bool isSlow = false;
  int dcol = 0, th = 0;
  size_t xbase = 0;
  if constexpr (MODE == 1) {
    isSlow = (bn >= 1024);
    const int dbase = isSlow ? (bn - 1024) : bn;
    const int bb = bm >> 11, t0 = bm & 2047, c0 = t0 >> 5;
    dcol = tid & 127; th = tid >> 7;              // th: t-half
    const int d = dbase + dcol;
    const float* gsp = isSlow ? sgs : fgs;
    const float* vsp = isSlow ? svs : fvs;
#pragma unroll
    for (int i = 0; i < 5; ++i) { gp *= gsp[i * 1024 + d]; vp *= vsp[i * 1024 + d]; }
    const float* Cp = isSlow ? CS : CF;
    hcar = Cp[bb * 65536 + (c0 + th * 2) * 1024 + d];   // single carry load
    xbase = ((size_t)(bb * 2048 + t0 + th * 64)) * 1024 + d;
  }

  f32x4 acc[AM][BT];
  const f32x4 z4 = {0.f, 0.f, 0.f, 0.f};
#pragma unroll
  for (int i = 0; i < AM; ++i)
#pragma unroll
    for (int j = 0; j < BT; ++j) acc[i][j] = z4;

  for (int k0 = 0; k0 < K; k0 += 64) {
#pragma unroll
    for (int j = 0; j < RA; ++j) cp16(gA[j] + k0, lA[j]);
#pragma unroll
    for (int j = 0; j < RB; ++j) cp16(gB[j] + k0, lB[j]);
    __syncthreads();
#pragma unroll
    for (int sub = 0; sub < 2; ++sub) {
      short8 af[AM], bf[BT];
#pragma unroll
      for (int mi = 0; mi < AM; ++mi) {
        const int row = wm + mi * 16 + fr;
        const int slot = (fq + sub * 4) ^ (row & 7);
        af[mi] = *(const short8*)&sA[row * 64 + slot * 8];
      }
#pragma unroll
      for (int ni = 0; ni < BT; ++ni) {
        const int row = wn + ni * 16 + fr;
        const int slot = (fq + sub * 4) ^ (row & 7);
        bf[ni] = *(const short8*)&sB[row * 64 + slot * 8];
      }
#pragma unroll
      for (int mi = 0; mi < AM; ++mi)
#pragma unroll
        for (int ni = 0; ni < BT; ++ni)
          acc[mi][ni] = __builtin_amdgcn_mfma_f32_16x16x32_bf16(
              af[mi], bf[ni], acc[mi][ni], 0, 0, 0);
    }
    __syncthreads();
  }

  // C/D layout: col = lane&15, row = (lane>>4)*4 + reg   [verified m89/m91]
  const int er0 = fq * 4;
  if constexpr (MODE == 1) {
    static_assert((BM + BN) * 64 >= 128 * 128, "sH needs 32KB");
    // ---- tail: rescan x -> sH (swizzled). Safe: all waves past last bar.
    unsigned short* sH = sAB;                      // [128 t][128 d] bf16
    float h = hcar;
#pragma unroll 8
    for (int tt = 0; tt < 64; ++tt) {
      float xv = xf[xbase + (size_t)tt * 1024];
      float f = sigmoidf_(xv * gp + 0.5f);
      if (isSlow) f = 0.85f + 0.15f * f;
      h = f * h + (1.f - f) * (xv * vp);
      const int row = th * 64 + tt;
      sH[row * 128 + (dcol ^ (((row >> 2) & 3) << 4))] = f2b(h);
    }
    __syncthreads();
    // ---- epilogue: sigmoid(C) * h, rowsum atomics ----
#pragma unroll
    for (int mi = 0; mi < AM; ++mi) {
#pragma unroll
      for (int r = 0; r < 4; ++r) {
        const int mo = wm + mi * 16 + er0 + r;     // row within band
        const int m = bm + mo;
        const int swz = ((mo >> 2) & 3) << 4;      // == fq<<4 (see header)
        float s = 0.f;
#pragma unroll
        for (int ni = 0; ni < BT; ++ni) {
          const int no = wn + ni * 16 + fr;        // col within tile
          float v = sigmoidf_(acc[mi][ni][r]) * b2f(sH[mo * 128 + (no ^ swz)]);
          merged[(size_t)m * 2048 + bn + no] = f2b(v);
          s += v * v;
        }
        s += __shfl_xor(s, 1); s += __shfl_xor(s, 2);
        s += __shfl_xor(s, 4); s += __shfl_xor(s, 8);
        if (fr == 0) atomicAdd(&rowsum[m], s);
      }
    }
  } else {
#pragma unroll
    for (int mi = 0; mi < AM; ++mi) {
#pragma unroll
      for (int r = 0; r < 4; ++r) {
        const int m = bm + wm + mi * 16 + er0 + r;
        const float rf = rsqrtf(rowsum[m] * (1.0f / 2048.0f) + 1e-6f);
#pragma unroll
        for (int ni = 0; ni < BT; ++ni) {
          const int n = bn + wn + ni * 16 + fr;
          out[(size_t)m * 1024 + n] = rf * acc[mi][ni][r];
        }
      }
    }
  }
}

// ---------------------------------------------------------------------------
extern "C" void kernel_launch(void* const* d_in, const int* in_sizes, int n_in,
                              void* d_out, int out_size, void* d_ws, size_t ws_size,
                              hipStream_t stream) {
  const float* x   = (const float*)d_in[0];
  const float* fgs = (const float*)d_in[1];
  const float* fvs = (const float*)d_in[2];
  const float* fow = (const float*)d_in[3];
  const float* sgs = (const float*)d_in[4];
  const float* svs = (const float*)d_in[5];
  const float* sow = (const float*)d_in[6];
  const float* mw  = (const float*)d_in[7];
  const float* nw  = (const float*)d_in[8];
  float* out = (float*)d_out;

  // compacted workspace (span 92 -> 62 MB)
  char* ws = (char*)d_ws;
  float* rowsum = (float*)(ws + 0);                         // 32 KB
  unsigned short* xb   = (unsigned short*)(ws + 32768);     // 16 MB
  unsigned short* wcat = (unsigned short*)(ws + 16809984);  // 4 MB
  unsigned short* w2   = (unsigned short*)(ws + 21004288);  // 4 MB
  float* PF = (float*)(ws + 25198592);                      // 1 MB each
  float* HF = (float*)(ws + 26247168);
  float* PS = (float*)(ws + 27295744);
  float* HS = (float*)(ws + 28344320);
  float* CF = (float*)(ws + 29392896);                      // 1 MB each
  float* CS = (float*)(ws + 30441472);
  unsigned short* mg = (unsigned short*)(ws + 31490048);    // 32 MB (end ~62MB)

  // scan (blocks 0..511, emits P/H + xb) + weight prep (blocks 512..4639)
  k_scanA<<<4640, 256, 0, stream>>>(x, fgs, fvs, sgs, svs, fow, sow, mw, nw,
                                    PF, HF, PS, HS, wcat, w2, rowsum, xb);
  // chunk-level carry table (tiny)
  k_prefix<<<16, 256, 0, stream>>>(PF, HF, PS, HS, CF, CS);
  // GEMM1: M=8192, N=2048, K=1024; tile 128x128; 64 bands x 16 cols
  // tail rebuilds h in-block from C + x (no hcat in HBM)
  k_gemm<64, 64, 1, 4><<<1024, 256, 0, stream>>>(
      xb, wcat, 1024, mg, rowsum, nullptr,
      x, fgs, fvs, sgs, svs, CF, CS);
  // GEMM2: M=8192, N=1024, K=2048; tile 64x128; 128 bands x 8 cols
  k_gemm<32, 64, 2, 3><<<1024, 256, 0, stream>>>(
      mg, w2, 2048, nullptr, rowsum, out,
      nullptr, nullptr, nullptr, nullptr, nullptr, nullptr, nullptr);
}